// Round 1
// baseline (812.567 us; speedup 1.0000x reference)
//
#include <hip/hip_runtime.h>
#include <stdint.h>

#define EPS_VAL 2.220446049250313e-16f

typedef unsigned short u16;
typedef __bf16 bf16x8 __attribute__((ext_vector_type(8)));
typedef float f32x4 __attribute__((ext_vector_type(4)));

static __device__ __forceinline__ u16 f2bf(float v) {
    __bf16 b = (__bf16)v;
    return __builtin_bit_cast(u16, b);
}
static __device__ __forceinline__ float bf2f(u16 u) {
    __bf16 b = __builtin_bit_cast(__bf16, u);
    return (float)b;
}

// ---------------- x -> bf16 ----------------
__global__ void k_cvt_x(const float* __restrict__ x, u16* __restrict__ xb) {
    int i = blockIdx.x * 256 + threadIdx.x;            // one uint4 (8 bf16) per thread
    const float4* p = (const float4*)x + (size_t)i * 2;
    float4 a = p[0], b = p[1];
    union { u16 h[8]; uint4 v; } o;
    o.h[0]=f2bf(a.x); o.h[1]=f2bf(a.y); o.h[2]=f2bf(a.z); o.h[3]=f2bf(a.w);
    o.h[4]=f2bf(b.x); o.h[5]=f2bf(b.y); o.h[6]=f2bf(b.z); o.h[7]=f2bf(b.w);
    *((uint4*)xb + i) = o.v;
}

// ---------------- transpose + convert: in [R][C] f32 -> out [C][R] bf16 ----------------
__global__ void k_transpose_cvt(const float* __restrict__ in, u16* __restrict__ out,
                                int R, int C) {
    __shared__ float t[32][33];
    const float* ip = in + (size_t)blockIdx.z * R * C;
    u16* op = out + (size_t)blockIdx.z * R * C;
    int tx = threadIdx.x & 31, ty = threadIdx.x >> 5;   // ty 0..7
    int c = blockIdx.x * 32 + tx;
    #pragma unroll
    for (int i = 0; i < 4; ++i) {
        int r = blockIdx.y * 32 + ty + i * 8;
        t[ty + i * 8][tx] = ip[(size_t)r * C + c];
    }
    __syncthreads();
    int r2 = blockIdx.y * 32 + tx;                      // output col = original row
    #pragma unroll
    for (int i = 0; i < 4; ++i) {
        int c2 = blockIdx.x * 32 + ty + i * 8;          // output row = original col
        op[(size_t)c2 * R + r2] = f2bf(t[tx][ty + i * 8]);
    }
}

// ---------------- gating: logits, top-2, softmax, build expert lists ----------------
__global__ void k_gate(const float* __restrict__ x, const float* __restrict__ wg,
                       int* __restrict__ cnt, uint2* __restrict__ asg,
                       float4* __restrict__ rec) {
    int row  = blockIdx.x * 4 + (threadIdx.x >> 6);
    int lane = threadIdx.x & 63;
    float a0=0,a1=0,a2=0,a3=0,a4=0,a5=0,a6=0,a7=0;
    #pragma unroll
    for (int it = 0; it < 8; ++it) {
        int d = it * 64 + lane;
        float xv = x[(size_t)row * 512 + d];
        const float4* wp = (const float4*)(wg + d * 8);
        float4 w0 = wp[0], w1 = wp[1];
        a0 += xv*w0.x; a1 += xv*w0.y; a2 += xv*w0.z; a3 += xv*w0.w;
        a4 += xv*w1.x; a5 += xv*w1.y; a6 += xv*w1.z; a7 += xv*w1.w;
    }
    #pragma unroll
    for (int off = 32; off; off >>= 1) {
        a0 += __shfl_xor(a0, off); a1 += __shfl_xor(a1, off);
        a2 += __shfl_xor(a2, off); a3 += __shfl_xor(a3, off);
        a4 += __shfl_xor(a4, off); a5 += __shfl_xor(a5, off);
        a6 += __shfl_xor(a6, off); a7 += __shfl_xor(a7, off);
    }
    if (lane == 0) {
        float v[8] = {a0,a1,a2,a3,a4,a5,a6,a7};
        int i0 = 0;
        #pragma unroll
        for (int e = 1; e < 8; ++e) if (v[e] > v[i0]) i0 = e;   // first max: lowest idx on tie
        int i1 = (i0 == 0) ? 1 : 0;
        #pragma unroll
        for (int e = 0; e < 8; ++e) if (e != i0 && v[e] > v[i1]) i1 = e;
        float ex = expf(v[i1] - v[i0]);
        float g0 = 1.f / (1.f + ex), g1 = ex / (1.f + ex);
        rec[row] = make_float4(__int_as_float(i0), __int_as_float(i1), g0, g1);
        if (i0 != 7) {
            int p = atomicAdd(&cnt[i0], 1);
            asg[i0 * 16384 + p] = make_uint2((unsigned)(row << 1), __float_as_uint(g0));
        }
        if (i1 != 7) {
            int p = atomicAdd(&cnt[i1], 1);
            asg[i1 * 16384 + p] = make_uint2((unsigned)((row << 1) | 1), __float_as_uint(g1));
        }
    }
}

// ---------------- fused per-expert MLP: Y = relu(X W1 + b1) W2 + b2, scatter g*Y ----------------
__global__ __launch_bounds__(512) void k_expert(
    const u16* __restrict__ xb,    // [N][512] bf16
    const u16* __restrict__ w1t,   // [7][2048][512] bf16 (W1^T per expert)
    const u16* __restrict__ w2t,   // [7][512][2048] bf16 (W2^T per expert)
    const float* __restrict__ b1,  // [7][2048]
    const float* __restrict__ b2,  // [7][512]
    const int* __restrict__ cnt,
    const uint2* __restrict__ asg, // [7][N]
    u16* __restrict__ ybuf)        // [2][N][512] bf16
{
    __shared__ __attribute__((aligned(16))) u16 Xs[64][520];   // rows x k, padded
    __shared__ __attribute__((aligned(16))) u16 W1s[32][520];  // h x k, padded
    __shared__ __attribute__((aligned(16))) u16 W2s[512][40];  // d x h_local, padded
    __shared__ __attribute__((aligned(16))) u16 Hs[64][40];    // rows x h_local, padded
    __shared__ int   rsl[64];
    __shared__ float gl[64];

    const int e    = blockIdx.y;
    const int base = blockIdx.x * 64;
    const int ce   = cnt[e];
    if (base >= ce) return;

    const int tid = threadIdx.x;
    if (tid < 64) {
        int idx = base + tid;
        if (idx < ce) {
            uint2 a = asg[e * 16384 + idx];
            rsl[tid] = (int)a.x;
            gl[tid]  = __builtin_bit_cast(float, a.y);
        } else { rsl[tid] = -1; gl[tid] = 0.f; }
    }
    __syncthreads();

    // stage X rows (64 x 512 bf16) into padded LDS
    for (int i = tid; i < 64 * 64; i += 512) {
        int r = i >> 6, c = i & 63;
        int rs = rsl[r];
        int grow = (rs < 0) ? 0 : (rs >> 1);
        uint4 v = *(const uint4*)(xb + (size_t)grow * 512 + c * 8);
        *(uint4*)&Xs[r][c * 8] = v;
    }
    __syncthreads();

    const int w    = tid >> 6;           // wave 0..7
    const int lane = tid & 63;
    const int l16  = lane & 15;
    const int kb   = (lane >> 4) * 8;    // 0,8,16,24

    // phase-1 A fragments in registers: rows rt..rt+15, K=512
    const int rt = (w >> 1) * 16;
    const int ct = (w & 1) * 16;
    bf16x8 xa[16];
    #pragma unroll
    for (int kk = 0; kk < 16; ++kk)
        xa[kk] = *(const bf16x8*)&Xs[rt + l16][kk * 32 + kb];

    f32x4 acc[4][4];
    #pragma unroll
    for (int mt = 0; mt < 4; ++mt)
        #pragma unroll
        for (int nt = 0; nt < 4; ++nt) acc[mt][nt] = (f32x4){0.f, 0.f, 0.f, 0.f};

    const u16* w1p = w1t + (size_t)e * 2048 * 512;
    const u16* w2p = w2t + (size_t)e * 512 * 2048;

    for (int hc = 0; hc < 2048; hc += 32) {
        // stage W1^T chunk: 32 (h) x 512 (k), contiguous source
        #pragma unroll
        for (int it = 0; it < 4; ++it) {
            int i = it * 512 + tid;
            int r = i >> 6, c = i & 63;
            uint4 v = *(const uint4*)(w1p + (size_t)(hc + r) * 512 + c * 8);
            *(uint4*)&W1s[r][c * 8] = v;
        }
        // stage W2^T chunk: 512 (d) x 32 (h), 64B-per-row strided source
        #pragma unroll
        for (int it = 0; it < 4; ++it) {
            int i = it * 512 + tid;
            int d = i >> 2, p = i & 3;
            uint4 v = *(const uint4*)(w2p + (size_t)d * 2048 + hc + p * 8);
            *(uint4*)&W2s[d][p * 8] = v;
        }
        __syncthreads();

        // phase 1: Hc tile [rt..rt+16) x [ct..ct+16), K=512
        f32x4 hacc = (f32x4){0.f, 0.f, 0.f, 0.f};
        #pragma unroll
        for (int kk = 0; kk < 16; ++kk) {
            bf16x8 bfr = *(const bf16x8*)&W1s[ct + l16][kk * 32 + kb];
            hacc = __builtin_amdgcn_mfma_f32_16x16x32_bf16(xa[kk], bfr, hacc, 0, 0, 0);
        }
        float bias = b1[e * 2048 + hc + ct + l16];
        #pragma unroll
        for (int r = 0; r < 4; ++r) {
            float v = hacc[r] + bias;
            v = v > 0.f ? v : 0.f;
            Hs[rt + (lane >> 4) * 4 + r][ct + l16] = f2bf(v);
        }
        __syncthreads();

        // phase 2: acc += Hs(64 x 32) @ W2s(32 x 64-col-slice)
        bf16x8 af[4], bfm[4];
        #pragma unroll
        for (int mt = 0; mt < 4; ++mt)
            af[mt] = *(const bf16x8*)&Hs[mt * 16 + l16][kb];
        #pragma unroll
        for (int nt = 0; nt < 4; ++nt)
            bfm[nt] = *(const bf16x8*)&W2s[w * 64 + nt * 16 + l16][kb];
        #pragma unroll
        for (int mt = 0; mt < 4; ++mt)
            #pragma unroll
            for (int nt = 0; nt < 4; ++nt)
                acc[mt][nt] = __builtin_amdgcn_mfma_f32_16x16x32_bf16(af[mt], bfm[nt], acc[mt][nt], 0, 0, 0);
        __syncthreads();
    }

    // epilogue: ybuf[slot][row][d] = bf16(g * (acc + b2))
    #pragma unroll
    for (int nt = 0; nt < 4; ++nt) {
        int d = w * 64 + nt * 16 + l16;
        float b2v = b2[e * 512 + d];
        #pragma unroll
        for (int mt = 0; mt < 4; ++mt) {
            #pragma unroll
            for (int r = 0; r < 4; ++r) {
                int m = mt * 16 + (lane >> 4) * 4 + r;
                int rs = rsl[m];
                if (rs >= 0) {
                    int grow = rs >> 1, slot = rs & 1;
                    float g = gl[m];
                    ybuf[((size_t)slot * 16384 + grow) * 512 + d] =
                        f2bf(g * (acc[mt][nt][r] + b2v));
                }
            }
        }
    }
}

// ---------------- final combine + EPS replacement ----------------
__global__ void k_final(const float* __restrict__ x, const float4* __restrict__ rec,
                        const u16* __restrict__ ybuf, float* __restrict__ out) {
    int i = blockIdx.x * 256 + threadIdx.x;     // one float4; total 16384*128
    int row = i >> 7;
    float4 r = rec[row];
    int e0 = __float_as_int(r.x), e1 = __float_as_int(r.y);
    float g7 = (e0 == 7) ? r.z : ((e1 == 7) ? r.w : 0.f);
    float4 xv = ((const float4*)x)[i];
    float o0 = g7 * xv.x, o1 = g7 * xv.y, o2 = g7 * xv.z, o3 = g7 * xv.w;
    size_t off = (size_t)i * 4;
    if (e0 != 7) {
        uint2 y = *(const uint2*)(ybuf + off);
        o0 += bf2f((u16)(y.x & 0xffff)); o1 += bf2f((u16)(y.x >> 16));
        o2 += bf2f((u16)(y.y & 0xffff)); o3 += bf2f((u16)(y.y >> 16));
    }
    if (e1 != 7) {
        uint2 y = *(const uint2*)(ybuf + 8388608 + off);
        o0 += bf2f((u16)(y.x & 0xffff)); o1 += bf2f((u16)(y.x >> 16));
        o2 += bf2f((u16)(y.y & 0xffff)); o3 += bf2f((u16)(y.y >> 16));
    }
    float4 res;
    res.x = (o0 == 0.f) ? EPS_VAL : o0;
    res.y = (o1 == 0.f) ? EPS_VAL : o1;
    res.z = (o2 == 0.f) ? EPS_VAL : o2;
    res.w = (o3 == 0.f) ? EPS_VAL : o3;
    ((float4*)out)[i] = res;
}

extern "C" void kernel_launch(void* const* d_in, const int* in_sizes, int n_in,
                              void* d_out, int out_size, void* d_ws, size_t ws_size,
                              hipStream_t stream) {
    const float* x  = (const float*)d_in[0];
    const float* wg = (const float*)d_in[1];
    const float* W1 = (const float*)d_in[2];
    const float* b1 = (const float*)d_in[3];
    const float* W2 = (const float*)d_in[4];
    const float* b2 = (const float*)d_in[5];

    char* ws = (char*)d_ws;
    // workspace layout (total ~77.1 MB)
    int*    cnt  = (int*)ws;                          // 32 B
    float4* rec  = (float4*)(ws + 256);               // 16384*16 = 262144
    uint2*  asg  = (uint2*)(ws + 262400);             // 7*16384*8 = 917504
    u16*    xb   = (u16*)(ws + 1179904);              // 16 MB
    u16*    w1t  = (u16*)(ws + 17957120);             // 14.68 MB
    u16*    w2t  = (u16*)(ws + 32637184);             // 14.68 MB
    u16*    ybuf = (u16*)(ws + 47317248);             // 32 MB bf16 (2 slots)

    hipMemsetAsync(cnt, 0, 32, stream);
    k_cvt_x<<<4096, 256, 0, stream>>>(x, xb);
    k_transpose_cvt<<<dim3(64, 16, 7), 256, 0, stream>>>(W1, w1t, 512, 2048);
    k_transpose_cvt<<<dim3(16, 64, 7), 256, 0, stream>>>(W2, w2t, 2048, 512);
    k_gate<<<4096, 256, 0, stream>>>(x, wg, cnt, asg, rec);
    k_expert<<<dim3(256, 7), 512, 0, stream>>>(xb, w1t, w2t, b1, b2, cnt, asg, ybuf);
    k_final<<<8192, 256, 0, stream>>>(x, rec, ybuf, (float*)d_out);
}